// Round 12
// baseline (133.848 us; speedup 1.0000x reference)
//
#include <hip/hip_runtime.h>
#include <hip/hip_bf16.h>

typedef __bf16 bf16x8 __attribute__((ext_vector_type(8)));
typedef float  f32x4  __attribute__((ext_vector_type(4)));

#define VOCAB 24
#define EDIM  16
#define HDIM  32
#define TLEN  128

union A2U { int4 w; bf16x8 v; };

__device__ __forceinline__ float ex2(float x)  { return __builtin_amdgcn_exp2f(x); }
__device__ __forceinline__ float rcpf_(float x){ return __builtin_amdgcn_rcpf(x); }
__device__ __forceinline__ int cvtpk(float lo, float hi) {
    int d;
    asm("v_cvt_pk_bf16_f32 %0, %1, %2" : "=v"(d) : "v"(lo), "v"(hi));
    return d;
}
// Redistribution mov: lanes l15>=8 (banks 2,3) receive src from lane l15-8
// (row_ror:8); lanes l15<8 keep 'oldv'. One DPP, no select.
__device__ __forceinline__ float dpp_upper(float oldv, float srcv) {
    int r = __builtin_amdgcn_update_dpp(__float_as_int(oldv), __float_as_int(srcv),
                                        0x128, 0xF, 0xC, false);
    return __int_as_float(r);
}

// 8 ROWS / WAVE, 2048 waves -> 2 waves/SIMD (R9/R10 showed 16 rows/wave
// pins the chip at 1 wave/SIMD and ~40% idle that neither ILP nor barrier
// flavor cures; this buys real TLP at the cost of half-wasted MFMA M-dim,
// which rides the separate matrix pipe anyway).
// Swapped-operand MFMA: gates^T = mfma(A=W-frags, B=onehot^T/h^T), so
// D[m=gatecol][n=row]; lane (l15,hi) holds rows=l15 (valid l15<8), gatecols
// 16nt+4hi+s. Tiles {2g,2g+1} = gate g over hidden j<16 / j>=16.
// After MFMA, 16 masked DPPs move the odd tiles to the idle l15>=8 lanes:
// lane l15<8 handles (row=l15, j=4hi+s), lane l15>=8 (row=l15-8, j=16+4hi+s)
// -> all 64 lanes active, 4 elements each, 32 trans/step (8/elem fused form).
// h-exchange for next B-frag: 2 cvtpk + 4 ds_bpermute (register-only).
// No barrier anywhere in the recurrence.
__global__ __launch_bounds__(64, 2) void lstm_fused(
    const int*   __restrict__ x,     // [B][128]
    const float* __restrict__ emb,   // [24][16]
    const float* __restrict__ W_ih,  // [128][16]
    const float* __restrict__ W_hh,  // [128][32]
    const float* __restrict__ b_ih,  // [128]
    const float* __restrict__ b_hh,  // [128]
    const float* __restrict__ fc_w,  // [2][32]
    const float* __restrict__ fc_b,  // [2]
    float*       __restrict__ out)   // [B][2]
{
    __shared__ __align__(16) float fbuf[8][33];   // final h (f32) for FC only

    const int lane  = threadIdx.x;       // 0..63
    const int l15   = lane & 15;
    const int hi    = lane >> 4;         // 0..3
    const int kh    = hi * 4;            // packed-word index base (k pairs)
    const int kbase = hi * 8;
    const int row0  = blockIdx.x * 8;
    const bool lowl = (l15 < 8);

    // ---- A-fragments (W), pre-scaled, registers ----
    // tile nt: gatecols 16nt..16nt+15, gate = nt>>1 (0=i,1=f,2=g,3=o).
    // A-frag: m = l15 (gatecol in tile), k = kbase+i.
    bf16x8 b1f[8];  // scale * W_hh
    bf16x8 b2f[8];  // scale * (emb[v].W_ih[gcol] + b_ih + b_hh), k = vocab v
    #pragma unroll
    for (int nt = 0; nt < 8; ++nt) {
        const int gcol = nt * 16 + l15;
        const float scale = ((nt >> 1) == 2) ? -2.88539008f : -1.44269504f;
        const float* wrow = W_hh + gcol * HDIM;
        #pragma unroll
        for (int i = 0; i < 8; ++i)
            b1f[nt][i] = (__bf16)(scale * wrow[kbase + i]);
        const float bias = b_ih[gcol] + b_hh[gcol];
        const float* wi = W_ih + gcol * EDIM;
        #pragma unroll
        for (int i = 0; i < 8; ++i) {
            const int v = kbase + i;
            float s = 0.0f;
            if (v < VOCAB) {
                s = bias;
                #pragma unroll
                for (int e = 0; e < EDIM; ++e)
                    s += emb[v * EDIM + e] * wi[e];
            }
            b2f[nt][i] = (__bf16)(scale * s);
        }
    }

    float c[4];
    #pragma unroll
    for (int s = 0; s < 4; ++s) c[s] = 0.0f;

    f32x4 p[8];                          // pipelined gates_x accumulators
    const f32x4 z = {0.f, 0.f, 0.f, 0.f};
    // tokens of this lane's B-column row (l15&7); l15>=8 duplicates -> always
    // in-bounds, feeds only the ignored D columns n>=8.
    const int* xrow = x + (row0 + (l15 & 7)) * TLEN;

    A2U hb; hb.w.x = hb.w.y = hb.w.z = hb.w.w = 0;

    // h-exchange source addresses (bytes, lane*4):
    // B word w of lane (l15,hi) comes from lane ((hi&1)*2 + (w>>1))*16
    //   + (l15 + 8*(hi>>1)); words 0,1 from source hh0, words 2,3 from hh0+16.
    const int srcA  = ((hi & 1) * 2) * 16 + l15 + 8 * (hi >> 1);
    const int addrA = 4 * srcA;
    const int addrB = addrA + 64;

    // final-h column base for fbuf / element identity
    const int jbase = (lowl ? 0 : 16) + 4 * hi;

// one-hot gates_x MFMAs for token XV -> p[] (one-hot as B-operand, n=row)
#define PRECOMP(XV) do {                                                       \
    const int xv_   = (XV);                                                    \
    const int hotw_ = 0x3F80 << ((xv_ & 1) << 4);                              \
    const int hoth_ = xv_ >> 1;                                                \
    A2U a2_;                                                                   \
    a2_.w.x = (hoth_ == kh + 0) ? hotw_ : 0;                                   \
    a2_.w.y = (hoth_ == kh + 1) ? hotw_ : 0;                                   \
    a2_.w.z = (hoth_ == kh + 2) ? hotw_ : 0;                                   \
    a2_.w.w = (hoth_ == kh + 3) ? hotw_ : 0;                                   \
    _Pragma("unroll")                                                          \
    for (int nt = 0; nt < 8; ++nt)                                             \
        p[nt] = __builtin_amdgcn_mfma_f32_16x16x32_bf16(b2f[nt], a2_.v, z, 0, 0, 0); \
} while (0)

// One timestep. On entry p[] holds this step's gates_x, hb the h B-fragment.
#define SLOT(FIRST, LAST, XVN) do {                                           \
    f32x4 acc_[8];                                                             \
    if (FIRST) {                                                               \
        _Pragma("unroll")                                                      \
        for (int nt = 0; nt < 8; ++nt) acc_[nt] = p[nt];                       \
    } else {                                                                   \
        _Pragma("unroll")                                                      \
        for (int nt = 0; nt < 8; ++nt)                                         \
            acc_[nt] = __builtin_amdgcn_mfma_f32_16x16x32_bf16(b1f[nt], hb.v, p[nt], 0, 0, 0); \
    }                                                                          \
    float av_[4][4];                                                           \
    _Pragma("unroll")                                                          \
    for (int g = 0; g < 4; ++g) {                                              \
        _Pragma("unroll")                                                      \
        for (int s = 0; s < 4; ++s)                                            \
            av_[g][s] = dpp_upper(acc_[2 * g][s], acc_[2 * g + 1][s]);         \
    }                                                                          \
    float hv_[4];                                                              \
    _Pragma("unroll")                                                          \
    for (int s = 0; s < 4; ++s) {                                              \
        const float ea = ex2(av_[0][s]);    /* i */                            \
        const float ew = ex2(av_[1][s]);    /* f */                            \
        const float eb = ex2(av_[2][s]);    /* g (2x scale) */                 \
        const float ev = ex2(av_[3][s]);    /* o */                            \
        const float R1 = rcpf_(1.0f + ew);                                     \
        const float R2 = rcpf_((1.0f + ea) * (1.0f + eb));                     \
        const float cc = fmaf(c[s], R1, (1.0f - eb) * R2);                     \
        c[s] = cc;                                                             \
        const float eu = ex2(cc * -2.88539008f);                               \
        const float R3 = rcpf_((1.0f + ev) * (1.0f + eu));                     \
        hv_[s] = (1.0f - eu) * R3;                                             \
    }                                                                          \
    if (LAST) {                                                                \
        _Pragma("unroll")                                                      \
        for (int s = 0; s < 4; ++s) fbuf[l15 & 7][jbase + s] = hv_[s];         \
    } else {                                                                   \
        const int w01 = cvtpk(hv_[0], hv_[1]);                                 \
        const int w23 = cvtpk(hv_[2], hv_[3]);                                 \
        hb.w.x = __builtin_amdgcn_ds_bpermute(addrA, w01);                     \
        hb.w.y = __builtin_amdgcn_ds_bpermute(addrA, w23);                     \
        hb.w.z = __builtin_amdgcn_ds_bpermute(addrB, w01);                     \
        hb.w.w = __builtin_amdgcn_ds_bpermute(addrB, w23);                     \
        PRECOMP(XVN);   /* independent MFMAs fill bpermute latency */          \
    }                                                                          \
} while (0)

    // ---- prologue: tokens 0-3 and 4-7; gates_x for t=0 ----
    int4 q0 = *(const int4*)xrow;
    int4 xq = *(const int4*)(xrow + 4);
    PRECOMP(q0.x);

    // t = 0..3
    SLOT(true,  false, q0.y);
    SLOT(false, false, q0.z);
    SLOT(false, false, q0.w);
    SLOT(false, false, xq.x);

    // main: t = 4..123, 4 steps/iter; tokens prefetched one iteration ahead
    #pragma unroll 1
    for (int t = 4; t < 124; t += 4) {
        const int4 n = *(const int4*)(xrow + t + 4);
        SLOT(false, false, xq.y);   // t
        SLOT(false, false, xq.z);   // t+1
        SLOT(false, false, xq.w);   // t+2
        SLOT(false, false, n.x);    // t+3
        xq = n;
    }

    // tail: t = 124..127
    SLOT(false, false, xq.y);       // 124
    SLOT(false, false, xq.z);       // 125
    SLOT(false, false, xq.w);       // 126
    SLOT(false, true,  0);          // 127 -> fbuf (f32)

#undef SLOT
#undef PRECOMP

    __syncthreads();   // single wave: guarantees fbuf writes drained

    // ---- FC epilogue: out[b] = h_last[b] @ fc_w^T + fc_b ----
    if (lane < 8) {
        float o0 = fc_b[0], o1 = fc_b[1];
        #pragma unroll
        for (int jj = 0; jj < HDIM; ++jj) {
            const float h = fbuf[lane][jj];
            o0 += fc_w[jj]        * h;
            o1 += fc_w[HDIM + jj] * h;
        }
        float2 res;
        res.x = o0; res.y = o1;
        *(float2*)&out[(row0 + lane) * 2] = res;
    }
}

extern "C" void kernel_launch(void* const* d_in, const int* in_sizes, int n_in,
                              void* d_out, int out_size, void* d_ws, size_t ws_size,
                              hipStream_t stream) {
    const int*   x    = (const int*)  d_in[0];
    const float* emb  = (const float*)d_in[1];
    const float* W_ih = (const float*)d_in[2];
    const float* W_hh = (const float*)d_in[3];
    const float* b_ih = (const float*)d_in[4];
    const float* b_hh = (const float*)d_in[5];
    const float* fc_w = (const float*)d_in[6];
    const float* fc_b = (const float*)d_in[7];
    float* out = (float*)d_out;

    const int B    = in_sizes[0] / TLEN;   // 16384
    const int nblk = B / 8;                // 2048 waves -> 2 per SIMD

    lstm_fused<<<nblk, 64, 0, stream>>>(x, emb, W_ih, W_hh, b_ih, b_hh, fc_w, fc_b, out);
}

// Round 13
// 105.106 us; speedup vs baseline: 1.2735x; 1.2735x over previous
//
#include <hip/hip_runtime.h>
#include <hip/hip_bf16.h>

typedef __bf16 bf16x8 __attribute__((ext_vector_type(8)));
typedef float  f32x4  __attribute__((ext_vector_type(4)));

#define VOCAB 24
#define EDIM  16
#define HDIM  32
#define TLEN  128

union A2U { int4 w; bf16x8 v; };

__device__ __forceinline__ float ex2(float x)  { return __builtin_amdgcn_exp2f(x); }
__device__ __forceinline__ float rcpf_(float x){ return __builtin_amdgcn_rcpf(x); }

// WAVE-PRIVATE design (R9 topology — best measured): block = 1 wave = 16
// batch rows, all 128 gate columns. No barrier, no cross-wave exchange.
// Per step: 8 one-hot MFMAs (gates_x, precomputed for next step) + 8 h-MFMAs.
// C-layout: acc value (nt, r) = gate col 16nt+l15, row 4hi+r. Element
// (row, j=qq*16+l15): i=acc[qq], f=acc[qq+2], g=acc[qq+4], o=acc[qq+6].
// h crosses lanes via wave-private LDS (in-order DS pipe, lgkm-only waits).
//
// R12 changes vs R9:
//  (1) fused-reciprocal activations, 7 trans/element (was 10):
//      ea,ew,eb,ev = exp2(pre-scaled accs); P=(1+ea)(1+eb);
//      c' = fmaf(c, P, (1-eb)(1+ew)) * rcp((1+ew)*P);
//      eu = exp2(-2log2e * c'); h = (1-eu) * rcp((1+ev)(1+eu)).
//      (B pre-scaled by -log2e for i,f,o and -2log2e for g.)
//  (2) h ds_read hoisted to right after the h-writes (same slot), so its
//      ~120cy latency hides under PRECOMP's independent MFMAs.
__global__ __launch_bounds__(64) void lstm_fused(
    const int*   __restrict__ x,     // [B][128]
    const float* __restrict__ emb,   // [24][16]
    const float* __restrict__ W_ih,  // [128][16]
    const float* __restrict__ W_hh,  // [128][32]
    const float* __restrict__ b_ih,  // [128]
    const float* __restrict__ b_hh,  // [128]
    const float* __restrict__ fc_w,  // [2][32]
    const float* __restrict__ fc_b,  // [2]
    float*       __restrict__ out)   // [B][2]
{
    __shared__ __align__(16) __bf16 hbuf[16][40];  // wave-private h, 80B rows
    __shared__ __align__(16) float  fbuf[16][33];  // final h (f32) for FC

    const int lane  = threadIdx.x;       // 0..63
    const int l15   = lane & 15;
    const int hi    = lane >> 4;         // 0..3
    const int kbase = hi * 8;
    const int kh    = hi * 4;            // packed-word index base
    const int row0  = blockIdx.x * 16;

    // ---- B-fragments for all 8 column tiles, pre-scaled, registers ----
    // tile nt: gate cols 16nt..16nt+15; gate id = nt>>1 (0=i,1=f,2=g,3=o).
    bf16x8 b1f[8];  // scale * W_hh^T
    bf16x8 b2f[8];  // scale * (emb[v].W_ih[gcol] + b_ih + b_hh)
    #pragma unroll
    for (int nt = 0; nt < 8; ++nt) {
        const int gcol = nt * 16 + l15;
        const float scale = ((nt >> 1) == 2) ? -2.88539008f : -1.44269504f;
        const float* wrow = W_hh + gcol * HDIM;
        #pragma unroll
        for (int i = 0; i < 8; ++i)
            b1f[nt][i] = (__bf16)(scale * wrow[kbase + i]);
        const float bias = b_ih[gcol] + b_hh[gcol];
        const float* wi = W_ih + gcol * EDIM;
        #pragma unroll
        for (int i = 0; i < 8; ++i) {
            const int v = kbase + i;
            float s = 0.0f;
            if (v < VOCAB) {
                s = bias;
                #pragma unroll
                for (int e = 0; e < EDIM; ++e)
                    s += emb[v * EDIM + e] * wi[e];
            }
            b2f[nt][i] = (__bf16)(scale * s);
        }
    }

    float c[8];
    #pragma unroll
    for (int q = 0; q < 8; ++q) c[q] = 0.0f;

    f32x4 p[8];                          // pipelined gates_x accumulators
    bf16x8 a1;                           // h fragment (read at END of prev slot)
    const f32x4 z = {0.f, 0.f, 0.f, 0.f};
    const int* xrow = x + (row0 + l15) * TLEN;

// one-hot gates_x MFMAs for token XV -> p[]
#define PRECOMP(XV) do {                                                       \
    const int xv_   = (XV);                                                    \
    const int hotw_ = 0x3F80 << ((xv_ & 1) << 4);                              \
    const int hoth_ = xv_ >> 1;                                                \
    A2U a2_;                                                                   \
    a2_.w.x = (hoth_ == kh + 0) ? hotw_ : 0;                                   \
    a2_.w.y = (hoth_ == kh + 1) ? hotw_ : 0;                                   \
    a2_.w.z = (hoth_ == kh + 2) ? hotw_ : 0;                                   \
    a2_.w.w = (hoth_ == kh + 3) ? hotw_ : 0;                                   \
    _Pragma("unroll")                                                          \
    for (int nt = 0; nt < 8; ++nt)                                             \
        p[nt] = __builtin_amdgcn_mfma_f32_16x16x32_bf16(a2_.v, b2f[nt], z, 0, 0, 0); \
} while (0)

// One timestep. On entry p[] = this step's gates_x, a1 = h fragment (t>0).
#define SLOT(FIRST, LAST, XVN) do {                                            \
    f32x4 acc_[8];                                                             \
    if (FIRST) {                                                               \
        _Pragma("unroll")                                                      \
        for (int nt = 0; nt < 8; ++nt) acc_[nt] = p[nt];                       \
    } else {                                                                   \
        _Pragma("unroll")                                                      \
        for (int nt = 0; nt < 8; ++nt)                                         \
            acc_[nt] = __builtin_amdgcn_mfma_f32_16x16x32_bf16(a1, b1f[nt], p[nt], 0, 0, 0); \
    }                                                                          \
    _Pragma("unroll")                                                          \
    for (int qq = 0; qq < 2; ++qq) {                                           \
        _Pragma("unroll")                                                      \
        for (int r = 0; r < 4; ++r) {                                          \
            const float ea = ex2(acc_[qq    ][r]);   /* i */                   \
            const float ew = ex2(acc_[qq + 2][r]);   /* f */                   \
            const float eb = ex2(acc_[qq + 4][r]);   /* g (2x scale) */        \
            const float ev = ex2(acc_[qq + 6][r]);   /* o */                   \
            const float P_ = (1.0f + ea) * (1.0f + eb);                        \
            const float N_ = fmaf(c[qq * 4 + r], P_, (1.0f - eb) * (1.0f + ew)); \
            const float cc = N_ * rcpf_((1.0f + ew) * P_);                     \
            c[qq * 4 + r] = cc;                                                \
            const float eu = ex2(cc * -2.88539008f);                           \
            const float hv = (1.0f - eu) * rcpf_((1.0f + ev) * (1.0f + eu));   \
            if (!(LAST)) hbuf[4 * hi + r][qq * 16 + l15] = (__bf16)hv;         \
            else         fbuf[4 * hi + r][qq * 16 + l15] = hv;                 \
        }                                                                      \
    }                                                                          \
    if (!(LAST)) {                                                             \
        a1 = *(const bf16x8*)&hbuf[l15][kbase];  /* hoisted next-step read */  \
        PRECOMP(XVN);          /* 8 indep MFMAs cover the ds_read latency */   \
    }                                                                          \
} while (0)

    // ---- prologue: tokens 0-3 and 4-7; gates_x for t=0 ----
    int4 q0 = *(const int4*)xrow;
    int4 xq = *(const int4*)(xrow + 4);
    PRECOMP(q0.x);

    // t = 0..3
    SLOT(true,  false, q0.y);
    SLOT(false, false, q0.z);
    SLOT(false, false, q0.w);
    SLOT(false, false, xq.x);

    // main: t = 4..123, 4 steps/iter; tokens prefetched one iteration ahead
    #pragma unroll 1
    for (int t = 4; t < 124; t += 4) {
        const int4 n = *(const int4*)(xrow + t + 4);
        SLOT(false, false, xq.y);   // t
        SLOT(false, false, xq.z);   // t+1
        SLOT(false, false, xq.w);   // t+2
        SLOT(false, false, n.x);    // t+3
        xq = n;
    }

    // tail: t = 124..127
    SLOT(false, false, xq.y);       // 124
    SLOT(false, false, xq.z);       // 125
    SLOT(false, false, xq.w);       // 126
    SLOT(false, true,  0);          // 127 -> fbuf (f32)

#undef SLOT
#undef PRECOMP

    __syncthreads();   // single wave: guarantees fbuf writes drained

    // ---- FC epilogue: out[b] = h_last[b] @ fc_w^T + fc_b ----
    if (lane < 16) {
        float o0 = fc_b[0], o1 = fc_b[1];
        #pragma unroll
        for (int jj = 0; jj < HDIM; ++jj) {
            const float h = fbuf[lane][jj];
            o0 += fc_w[jj]        * h;
            o1 += fc_w[HDIM + jj] * h;
        }
        float2 res;
        res.x = o0; res.y = o1;
        *(float2*)&out[(row0 + lane) * 2] = res;
    }
}

extern "C" void kernel_launch(void* const* d_in, const int* in_sizes, int n_in,
                              void* d_out, int out_size, void* d_ws, size_t ws_size,
                              hipStream_t stream) {
    const int*   x    = (const int*)  d_in[0];
    const float* emb  = (const float*)d_in[1];
    const float* W_ih = (const float*)d_in[2];
    const float* W_hh = (const float*)d_in[3];
    const float* b_ih = (const float*)d_in[4];
    const float* b_hh = (const float*)d_in[5];
    const float* fc_w = (const float*)d_in[6];
    const float* fc_b = (const float*)d_in[7];
    float* out = (float*)d_out;

    const int B    = in_sizes[0] / TLEN;   // 16384
    const int nblk = B / 16;               // 1024 waves, 1 per SIMD chip-wide

    lstm_fused<<<nblk, 64, 0, stream>>>(x, emb, W_ih, W_hh, b_ih, b_hh, fc_w, fc_b, out);
}

// Round 14
// 103.061 us; speedup vs baseline: 1.2987x; 1.0198x over previous
//
#include <hip/hip_runtime.h>
#include <hip/hip_bf16.h>

typedef __bf16 bf16x8 __attribute__((ext_vector_type(8)));
typedef float  f32x4  __attribute__((ext_vector_type(4)));

#define VOCAB 24
#define EDIM  16
#define HDIM  32
#define TLEN  128

union A2U { int4 w; bf16x8 v; };

__device__ __forceinline__ float ex2(float x)  { return __builtin_amdgcn_exp2f(x); }
__device__ __forceinline__ float rcpf_(float x){ return __builtin_amdgcn_rcpf(x); }

// WAVE-PRIVATE design (R9/R12 topology — best measured): block = 1 wave =
// 16 batch rows, all 128 gate columns. No barrier, no cross-wave exchange.
// Per step: 8 one-hot MFMAs (gates_x for NEXT step) + 8 h-MFMAs.
// C-layout: acc value (nt, r) = gate col 16nt+l15, row 4hi+r. Element
// (row, j=qq*16+l15): i=acc[qq], f=acc[qq+2], g=acc[qq+4], o=acc[qq+6].
// h crosses lanes via wave-private LDS (in-order DS pipe, lgkm waits only).
//
// R13 changes vs R12:
//  (1) SoA-batched GUPD: all 32 independent exp2 issued in one flat pass,
//      then the dependent VALU/rcp/exp2 pass (gives the quarter-rate trans
//      pipe an uninterrupted run + cross-element overlap).
//  (2) c kept in pre-scaled domain d = -2*log2e*c:
//      d' = fmaf(d, P, fmaf(2.885..., eb, -2.885...)*T) * rcp(T*P),
//      eu = ex2(d'), removing the multiply from the serial c-chain.
//      (B pre-scaled by -log2e for i,f,o and -2log2e for g, as before:
//       ea,ew,eb,ev = exp2 of accs; P=(1+ea)(1+eb); T=(1+ew);
//       h = (1-eu)*rcp((1+ev)(1+eu)).)
__global__ __launch_bounds__(64) void lstm_fused(
    const int*   __restrict__ x,     // [B][128]
    const float* __restrict__ emb,   // [24][16]
    const float* __restrict__ W_ih,  // [128][16]
    const float* __restrict__ W_hh,  // [128][32]
    const float* __restrict__ b_ih,  // [128]
    const float* __restrict__ b_hh,  // [128]
    const float* __restrict__ fc_w,  // [2][32]
    const float* __restrict__ fc_b,  // [2]
    float*       __restrict__ out)   // [B][2]
{
    __shared__ __align__(16) __bf16 hbuf[16][40];  // wave-private h, 80B rows
    __shared__ __align__(16) float  fbuf[16][33];  // final h (f32) for FC

    const int lane  = threadIdx.x;       // 0..63
    const int l15   = lane & 15;
    const int hi    = lane >> 4;         // 0..3
    const int kbase = hi * 8;
    const int kh    = hi * 4;            // packed-word index base
    const int row0  = blockIdx.x * 16;

    // ---- B-fragments for all 8 column tiles, pre-scaled, registers ----
    // tile nt: gate cols 16nt..16nt+15; gate id = nt>>1 (0=i,1=f,2=g,3=o).
    bf16x8 b1f[8];  // scale * W_hh^T
    bf16x8 b2f[8];  // scale * (emb[v].W_ih[gcol] + b_ih + b_hh)
    #pragma unroll
    for (int nt = 0; nt < 8; ++nt) {
        const int gcol = nt * 16 + l15;
        const float scale = ((nt >> 1) == 2) ? -2.88539008f : -1.44269504f;
        const float* wrow = W_hh + gcol * HDIM;
        #pragma unroll
        for (int i = 0; i < 8; ++i)
            b1f[nt][i] = (__bf16)(scale * wrow[kbase + i]);
        const float bias = b_ih[gcol] + b_hh[gcol];
        const float* wi = W_ih + gcol * EDIM;
        #pragma unroll
        for (int i = 0; i < 8; ++i) {
            const int v = kbase + i;
            float s = 0.0f;
            if (v < VOCAB) {
                s = bias;
                #pragma unroll
                for (int e = 0; e < EDIM; ++e)
                    s += emb[v * EDIM + e] * wi[e];
            }
            b2f[nt][i] = (__bf16)(scale * s);
        }
    }

    float d[8];                          // d = -2*log2e * c  (scaled domain)
    #pragma unroll
    for (int q = 0; q < 8; ++q) d[q] = 0.0f;

    f32x4 p[8];                          // pipelined gates_x accumulators
    bf16x8 a1;                           // h fragment (read at END of prev slot)
    const f32x4 z = {0.f, 0.f, 0.f, 0.f};
    const int* xrow = x + (row0 + l15) * TLEN;

// one-hot gates_x MFMAs for token XV -> p[]
#define PRECOMP(XV) do {                                                       \
    const int xv_   = (XV);                                                    \
    const int hotw_ = 0x3F80 << ((xv_ & 1) << 4);                              \
    const int hoth_ = xv_ >> 1;                                                \
    A2U a2_;                                                                   \
    a2_.w.x = (hoth_ == kh + 0) ? hotw_ : 0;                                   \
    a2_.w.y = (hoth_ == kh + 1) ? hotw_ : 0;                                   \
    a2_.w.z = (hoth_ == kh + 2) ? hotw_ : 0;                                   \
    a2_.w.w = (hoth_ == kh + 3) ? hotw_ : 0;                                   \
    _Pragma("unroll")                                                          \
    for (int nt = 0; nt < 8; ++nt)                                             \
        p[nt] = __builtin_amdgcn_mfma_f32_16x16x32_bf16(a2_.v, b2f[nt], z, 0, 0, 0); \
} while (0)

// One timestep. On entry p[] = this step's gates_x, a1 = h fragment (t>0).
#define SLOT(FIRST, LAST, XVN) do {                                            \
    f32x4 acc_[8];                                                             \
    if (FIRST) {                                                               \
        _Pragma("unroll")                                                      \
        for (int nt = 0; nt < 8; ++nt) acc_[nt] = p[nt];                       \
    } else {                                                                   \
        _Pragma("unroll")                                                      \
        for (int nt = 0; nt < 8; ++nt)                                         \
            acc_[nt] = __builtin_amdgcn_mfma_f32_16x16x32_bf16(a1, b1f[nt], p[nt], 0, 0, 0); \
    }                                                                          \
    /* ---- SoA pass 1: 32 independent exp2 ---- */                            \
    float ea_[8], ew_[8], eb_[8], ev_[8];                                      \
    _Pragma("unroll")                                                          \
    for (int k = 0; k < 8; ++k) {                                              \
        const int qq_ = k >> 2, r_ = k & 3;                                    \
        ea_[k] = ex2(acc_[qq_    ][r_]);   /* i */                             \
        ew_[k] = ex2(acc_[qq_ + 2][r_]);   /* f */                             \
        eb_[k] = ex2(acc_[qq_ + 4][r_]);   /* g (2x scale) */                  \
        ev_[k] = ex2(acc_[qq_ + 6][r_]);   /* o */                             \
    }                                                                          \
    /* ---- SoA pass 2: dependent VALU / rcp / exp2, then write ---- */        \
    _Pragma("unroll")                                                          \
    for (int k = 0; k < 8; ++k) {                                              \
        const int qq_ = k >> 2, r_ = k & 3;                                    \
        const float P_ = (1.0f + ea_[k]) * (1.0f + eb_[k]);                    \
        const float T_ = 1.0f + ew_[k];                                        \
        const float G_ = fmaf(2.88539008f, eb_[k], -2.88539008f);              \
        const float N_ = fmaf(d[k], P_, G_ * T_);                              \
        const float dd = N_ * rcpf_(T_ * P_);                                  \
        d[k] = dd;                                                             \
        const float eu = ex2(dd);                                              \
        const float hv = (1.0f - eu) * rcpf_((1.0f + ev_[k]) * (1.0f + eu));   \
        if (!(LAST)) hbuf[4 * hi + r_][qq_ * 16 + l15] = (__bf16)hv;           \
        else         fbuf[4 * hi + r_][qq_ * 16 + l15] = hv;                   \
    }                                                                          \
    if (!(LAST)) {                                                             \
        a1 = *(const bf16x8*)&hbuf[l15][kbase];  /* hoisted next-step read */  \
        PRECOMP(XVN);          /* 8 indep MFMAs cover the ds_read latency */   \
    }                                                                          \
} while (0)

    // ---- prologue: tokens 0-3 and 4-7; gates_x for t=0 ----
    int4 q0 = *(const int4*)xrow;
    int4 xq = *(const int4*)(xrow + 4);
    PRECOMP(q0.x);

    // t = 0..3
    SLOT(true,  false, q0.y);
    SLOT(false, false, q0.z);
    SLOT(false, false, q0.w);
    SLOT(false, false, xq.x);

    // main: t = 4..123, 4 steps/iter; tokens prefetched one iteration ahead
    #pragma unroll 1
    for (int t = 4; t < 124; t += 4) {
        const int4 n = *(const int4*)(xrow + t + 4);
        SLOT(false, false, xq.y);   // t
        SLOT(false, false, xq.z);   // t+1
        SLOT(false, false, xq.w);   // t+2
        SLOT(false, false, n.x);    // t+3
        xq = n;
    }

    // tail: t = 124..127
    SLOT(false, false, xq.y);       // 124
    SLOT(false, false, xq.z);       // 125
    SLOT(false, false, xq.w);       // 126
    SLOT(false, true,  0);          // 127 -> fbuf (f32)

#undef SLOT
#undef PRECOMP

    __syncthreads();   // single wave: guarantees fbuf writes drained

    // ---- FC epilogue: out[b] = h_last[b] @ fc_w^T + fc_b ----
    if (lane < 16) {
        float o0 = fc_b[0], o1 = fc_b[1];
        #pragma unroll
        for (int jj = 0; jj < HDIM; ++jj) {
            const float h = fbuf[lane][jj];
            o0 += fc_w[jj]        * h;
            o1 += fc_w[HDIM + jj] * h;
        }
        float2 res;
        res.x = o0; res.y = o1;
        *(float2*)&out[(row0 + lane) * 2] = res;
    }
}

extern "C" void kernel_launch(void* const* d_in, const int* in_sizes, int n_in,
                              void* d_out, int out_size, void* d_ws, size_t ws_size,
                              hipStream_t stream) {
    const int*   x    = (const int*)  d_in[0];
    const float* emb  = (const float*)d_in[1];
    const float* W_ih = (const float*)d_in[2];
    const float* W_hh = (const float*)d_in[3];
    const float* b_ih = (const float*)d_in[4];
    const float* b_hh = (const float*)d_in[5];
    const float* fc_w = (const float*)d_in[6];
    const float* fc_b = (const float*)d_in[7];
    float* out = (float*)d_out;

    const int B    = in_sizes[0] / TLEN;   // 16384
    const int nblk = B / 16;               // 1024 waves, 1 per SIMD chip-wide

    lstm_fused<<<nblk, 64, 0, stream>>>(x, emb, W_ih, W_hh, b_ih, b_hh, fc_w, fc_b, out);
}